// Round 4
// baseline (218.716 us; speedup 1.0000x reference)
//
#include <hip/hip_runtime.h>
#include <math.h>

// VQ-VAE quantize: z [32,8,16,16] f32, codebook [16384,8] f32
// N=8192 rows, K=16384 codes, D=8.
// Outputs (concatenated f32): z_q [65536], loss [1], idx-as-float [8192].
//
// f[n,k] = 200*dot(z_n,e_k) - 100*||e_k||^2 (softmax/argmax shift-invariant;
// T=0.01). exp underflows for f-m < -87 (bit-matches fp32 reference: such
// terms add < 2e-38 to s ~ 1 -> no effect).
//
// R3 lesson: per-wave codebook re-reads from L2 (2.36 GB) were the wall
// (~337 cyc/iter regardless of VALU load). Now: codebook staged via LDS
// double-buffered tiles, 8 rows/wave (amortize each staged byte 8x), inner
// loop = pure LDS reads + FMA. Candidates -> one block-wide LDS buffer;
// per-row threshold via LDS atomicMax; in-block exact fallback on overflow.

#define KCODES 16384
#define TILE   512
#define NTILES 32
#define CAP    2048

__device__ __forceinline__ float dot8v(const float* zr, float4 L, float4 H,
                                       float b) {
    float a = fmaf(zr[0], L.x, b);
    a = fmaf(zr[1], L.y, a);
    a = fmaf(zr[2], L.z, a);
    a = fmaf(zr[3], L.w, a);
    a = fmaf(zr[4], H.x, a);
    a = fmaf(zr[5], H.y, a);
    a = fmaf(zr[6], H.z, a);
    a = fmaf(zr[7], H.w, a);
    return a;
}

// order-preserving float<->int for LDS atomicMax (no NaNs here)
__device__ __forceinline__ int encf(float f) {
    int i = __float_as_int(f);
    return i < 0 ? (i ^ 0x7fffffff) : i;
}
__device__ __forceinline__ float decf(int i) {
    return __int_as_float(i < 0 ? (i ^ 0x7fffffff) : i);
}

// ---------------- prep: codebook norms ----------------
__global__ __launch_bounds__(256) void prep_cb(const float* __restrict__ cb,
                                               float* __restrict__ bk) {
    int k = blockIdx.x * 256 + threadIdx.x;
    const float4* c4 = (const float4*)cb;
    float4 c0 = c4[2 * k], c1 = c4[2 * k + 1];
    float nrm = c0.x * c0.x + c0.y * c0.y + c0.z * c0.z + c0.w * c0.w
              + c1.x * c1.x + c1.y * c1.y + c1.z * c1.z + c1.w * c1.w;
    bk[k] = -100.0f * nrm;
}

// ---------------- pass 1 ----------------
__global__ __launch_bounds__(256, 1) void pass1(
    const float* __restrict__ z, const float* __restrict__ cb,
    const float* __restrict__ bkg, float* __restrict__ out_zq,
    float* __restrict__ out_idx, float* __restrict__ scal,
    float* __restrict__ avgp)
{
    __shared__ float4 lo[2][TILE];     // dims 0-3, stride 16B (good b128)
    __shared__ float4 hi[2][TILE];     // dims 4-7
    __shared__ float  bkt[2][TILE];
    __shared__ int    kr[CAP];         // (k<<5)|row_local
    __shared__ float  fr[CAP];
    __shared__ int    cnt;
    __shared__ int    mI[32];          // per-row running max (encoded)
    __shared__ float  m_f[32], s_sh[32], t_sh[32];
    __shared__ int    kmin_sh[32];

    const int tid  = threadIdx.x;
    const int wave = tid >> 6;
    const int lane = tid & 63;
    const int wrow0 = wave * 8;                  // block-local first row
    const int growbase = blockIdx.x * 32;

    // ---- load this wave's 8 rows, fold 200x scale ----
    float za[8][8];
#pragma unroll
    for (int r = 0; r < 8; ++r) {
        int row = growbase + wrow0 + r;
        int bb = row >> 8, hw = row & 255;
        const float* p = z + bb * 2048 + hw;
#pragma unroll
        for (int c = 0; c < 8; ++c) za[r][c] = 200.0f * p[c * 256];
    }
    if (tid == 0) cnt = 0;

    const float4* cbv = (const float4*)cb;

    // staging registers
    float4 l0, h0, l1, h1; float b0, b1;
#define STAGE_LD(t)  { int k0 = (t) * TILE + tid, k1 = k0 + 256;          \
        l0 = cbv[2 * k0]; h0 = cbv[2 * k0 + 1];                           \
        l1 = cbv[2 * k1]; h1 = cbv[2 * k1 + 1];                           \
        b0 = bkg[k0]; b1 = bkg[k1]; }
#define STAGE_WR(bf) { lo[bf][tid] = l0; hi[bf][tid] = h0;                \
        lo[bf][tid + 256] = l1; hi[bf][tid + 256] = h1;                   \
        bkt[bf][tid] = b0; bkt[bf][tid + 256] = b1; }

    STAGE_LD(0); STAGE_WR(0);
    __syncthreads();

    // ---- warm-up A: exact max over tile 0 (no recording) ----
    float mt[8];
    {
        float wm[8];
#pragma unroll
        for (int r = 0; r < 8; ++r) wm[r] = -3.4e38f;
#pragma unroll
        for (int j = 0; j < 8; ++j) {
            int ci = j * 64 + lane;
            float4 L = lo[0][ci], H = hi[0][ci];
            float b = bkt[0][ci];
#pragma unroll
            for (int r = 0; r < 8; ++r) wm[r] = fmaxf(wm[r], dot8v(za[r], L, H, b));
        }
#pragma unroll
        for (int r = 0; r < 8; ++r) {
#pragma unroll
            for (int off = 32; off; off >>= 1) wm[r] = fmaxf(wm[r], __shfl_xor(wm[r], off));
            mt[r] = wm[r] - 87.0f;
        }
        if (lane == 0) {
#pragma unroll
            for (int r = 0; r < 8; ++r) mI[wrow0 + r] = encf(wm[r]);
        }
    }

    STAGE_LD(1);   // issue tile-1 loads; hidden under warm-up B

    // ---- warm-up B: re-scan tile 0 with recording (tight threshold) ----
#pragma unroll 2
    for (int j = 0; j < 8; ++j) {
        int ci = j * 64 + lane;
        float4 L = lo[0][ci], H = hi[0][ci];
        float b = bkt[0][ci];
        float fv[8];
#pragma unroll
        for (int r = 0; r < 8; ++r) fv[r] = dot8v(za[r], L, H, b);
        int hh = 0;
#pragma unroll
        for (int r = 0; r < 8; ++r) hh |= (fv[r] > mt[r]);
        if (__any(hh)) {
#pragma unroll
            for (int r = 0; r < 8; ++r) {
                if (fv[r] > mt[r]) {
                    mt[r] = fmaxf(mt[r], fv[r] - 87.0f);
                    atomicMax(&mI[wrow0 + r], encf(fv[r]));
                    int pos = atomicAdd(&cnt, 1);
                    if (pos < CAP) { kr[pos] = (ci << 5) | (wrow0 + r); fr[pos] = fv[r]; }
                }
            }
        }
    }
    STAGE_WR(1);
    __syncthreads();

    // ---- main sweep: tiles 1..31, double-buffered ----
    for (int t = 1; t < NTILES; ++t) {
        const int bf = t & 1;
        const int tbase = t * TILE;
        const bool more = (t + 1 < NTILES);
        if (more) STAGE_LD(t + 1);
#pragma unroll 2
        for (int j = 0; j < 8; ++j) {
            int ci = j * 64 + lane;
            float4 L = lo[bf][ci], H = hi[bf][ci];
            float b = bkt[bf][ci];
            float fv[8];
#pragma unroll
            for (int r = 0; r < 8; ++r) fv[r] = dot8v(za[r], L, H, b);
            int hh = 0;
#pragma unroll
            for (int r = 0; r < 8; ++r) hh |= (fv[r] > mt[r]);
            if (__any(hh)) {
#pragma unroll
                for (int r = 0; r < 8; ++r) {
                    if (fv[r] > mt[r]) {
                        mt[r] = fmaxf(mt[r], fv[r] - 87.0f);
                        atomicMax(&mI[wrow0 + r], encf(fv[r]));
                        int pos = atomicAdd(&cnt, 1);
                        if (pos < CAP) { kr[pos] = ((tbase + ci) << 5) | (wrow0 + r); fr[pos] = fv[r]; }
                    }
                }
            }
        }
        if (t & 1) {   // refresh thresholds from wave-global running max
#pragma unroll
            for (int r = 0; r < 8; ++r)
                mt[r] = fmaxf(mt[r], decf(mI[wrow0 + r]) - 87.0f);
        }
        if (more) STAGE_WR((t + 1) & 1);
        __syncthreads();
    }

    const int total = cnt;
    if (total <= CAP) {
        // ---------------- normal flush ----------------
        if (tid < 32) {
            m_f[tid] = decf(mI[tid]);
            s_sh[tid] = 0.0f; t_sh[tid] = 0.0f; kmin_sh[tid] = 0x7fffffff;
        }
        __syncthreads();
        for (int i = tid; i < total; i += 256) {
            int pk = kr[i]; int row = pk & 31; int k = pk >> 5;
            float x = fr[i] - m_f[row];
            if (x > -87.0f) {
                float e = __expf(x);
                atomicAdd(&s_sh[row], e);
                atomicAdd(&t_sh[row], x * e);
                if (x == 0.0f) atomicMin(&kmin_sh[row], k);
            }
        }
        __syncthreads();
        for (int i = tid; i < total; i += 256) {
            int pk = kr[i]; int row = pk & 31; int k = pk >> 5;
            float x = fr[i] - m_f[row];
            if (x > -87.0f) atomicAdd(&avgp[k], __expf(x) / s_sh[row]);
        }
        float entL = 0.0f, sqL = 0.0f;
        if (tid < 32) {
            int rowg = growbase + tid;
            float s = s_sh[tid], t = t_sh[tid];
            entL = t / s - logf(s);
            int km = kmin_sh[tid];
            out_idx[rowg] = (float)km;
            float4 q0 = cbv[2 * km], q1 = cbv[2 * km + 1];
            float qv[8] = {q0.x, q0.y, q0.z, q0.w, q1.x, q1.y, q1.z, q1.w};
            int bb = rowg >> 8, hw = rowg & 255;
            const float* zp = z + bb * 2048 + hw;
            float* o = out_zq + bb * 2048 + hw;
#pragma unroll
            for (int c = 0; c < 8; ++c) {
                float raw = zp[c * 256];
                o[c * 256] = qv[c];
                float dq = qv[c] - raw;
                sqL += dq * dq;
            }
        }
        if (tid < 64) {   // wave 0 reduce (lanes >=32 carry zeros)
#pragma unroll
            for (int off = 32; off; off >>= 1) {
                entL += __shfl_xor(entL, off);
                sqL  += __shfl_xor(sqL, off);
            }
            if (tid == 0) {
                atomicAdd(&scal[0], sqL);
                atomicAdd(&scal[1], entL);
            }
        }
    } else {
        // ------------- overflow fallback: exact per-wave recompute -------
        // (never expected; correctness net, block-local, deterministic)
        float entW = 0.0f, sqW = 0.0f;
#pragma unroll 1
        for (int r = 0; r < 8; ++r) {
            int rowg = growbase + wrow0 + r;
            float m = -3.4e38f, s = 0.0f, t = 0.0f;
            int kloc = 0x7fffffff;
            for (int k = lane; k < KCODES; k += 64) {
                float f = dot8v(za[r], cbv[2 * k], cbv[2 * k + 1], bkg[k]);
                float x = f - m;
                if (x > 0.0f) {
                    float fsc = __expf(-x);
                    t = fsc * fmaf(-x, s, t);
                    s = fmaf(s, fsc, 1.0f);
                    m = f; kloc = k;
                } else if (x > -87.0f) {
                    float e = __expf(x);
                    s += e; t = fmaf(x, e, t);
                }
            }
            for (int off = 32; off; off >>= 1) {
                float mo = __shfl_xor(m, off);
                float so = __shfl_xor(s, off);
                float to = __shfl_xor(t, off);
                int   ko = __shfl_xor(kloc, off);
                float mn = fmaxf(m, mo);
                float d1 = m - mn, d2 = mo - mn;
                float f1 = __expf(d1), f2 = __expf(d2);
                t = f1 * fmaf(d1, s, t) + f2 * fmaf(d2, so, to);
                s = f1 * s + f2 * so;
                kloc = (m > mo) ? kloc : ((mo > m) ? ko : (kloc < ko ? kloc : ko));
                m = mn;
            }
            // all lanes hold merged m,s,t,kloc
            float rs = 1.0f / s;
            for (int k = lane; k < KCODES; k += 64) {
                float f = dot8v(za[r], cbv[2 * k], cbv[2 * k + 1], bkg[k]);
                float x = f - m;
                if (x > -87.0f) atomicAdd(&avgp[k], __expf(x) * rs);
            }
            if (lane == 0) {
                entW += t * rs - logf(s);
                out_idx[rowg] = (float)kloc;
                float4 q0 = cbv[2 * kloc], q1 = cbv[2 * kloc + 1];
                float qv[8] = {q0.x, q0.y, q0.z, q0.w, q1.x, q1.y, q1.z, q1.w};
                int bb = rowg >> 8, hw = rowg & 255;
                const float* zp = z + bb * 2048 + hw;
                float* o = out_zq + bb * 2048 + hw;
#pragma unroll
                for (int c = 0; c < 8; ++c) {
                    float raw = zp[c * 256];
                    o[c * 256] = qv[c];
                    float dq = qv[c] - raw;
                    sqW += dq * dq;
                }
            }
        }
        if (lane == 0) {
            atomicAdd(&scal[0], sqW);
            atomicAdd(&scal[1], entW);
        }
    }
#undef STAGE_LD
#undef STAGE_WR
}

// ---------------- finalize: avg entropy + loss assembly ----------------
__global__ __launch_bounds__(256) void finalize(
    const float* __restrict__ avgp, const float* __restrict__ scal,
    float* __restrict__ out_loss)
{
    float acc = 0.0f;
    for (int k = threadIdx.x; k < KCODES; k += 256) {
        float avg = avgp[k] * (1.0f / 8192.0f);
        acc += avg * logf(avg + 1e-5f);    // avg==0 contributes exactly 0
    }
#pragma unroll
    for (int off = 32; off > 0; off >>= 1) acc += __shfl_xor(acc, off);
    __shared__ float red[4];
    int wave = threadIdx.x >> 6, lane = threadIdx.x & 63;
    if (lane == 0) red[wave] = acc;
    __syncthreads();
    if (threadIdx.x == 0) {
        float T = red[0] + red[1] + red[2] + red[3];   // sum avg*log(avg+eps)
        // loss = 1.25*mean((zq-z)^2) + 0.1*(sample_entropy - avg_entropy)
        float loss = 1.25f * (scal[0] * (1.0f / 65536.0f))
                   + 0.1f * (T - scal[1] * (1.0f / 8192.0f));
        out_loss[0] = loss;
    }
}

extern "C" void kernel_launch(void* const* d_in, const int* in_sizes, int n_in,
                              void* d_out, int out_size, void* d_ws, size_t ws_size,
                              hipStream_t stream) {
    const float* z  = (const float*)d_in[0];   // [32,8,16,16]
    const float* cb = (const float*)d_in[1];   // [16384,8]
    float* out = (float*)d_out;
    float* ws  = (float*)d_ws;

    // workspace layout (floats)
    float* bk   = ws;                // 16384 : -100*||e_k||^2
    float* avgp = ws + 16384;        // 16384 : sum_n p[n,k]
    float* scal = ws + 32768;        // 2     : [sq, entS]

    float* out_zq   = out;           // 65536
    float* out_loss = out + 65536;   // 1
    float* out_idx  = out + 65537;   // 8192

    hipMemsetAsync(avgp, 0, (16384 + 8) * sizeof(float), stream);

    prep_cb <<<64,  256, 0, stream>>>(cb, bk);
    pass1   <<<256, 256, 0, stream>>>(z, cb, bk, out_zq, out_idx, scal, avgp);
    finalize<<<1,   256, 0, stream>>>(avgp, scal, out_loss);
}